// Round 9
// baseline (269.425 us; speedup 1.0000x reference)
//
#include <hip/hip_runtime.h>
#include <hip/hip_bf16.h>

typedef unsigned int u32;
typedef unsigned short u16;
typedef unsigned long long u64;
typedef __attribute__((ext_vector_type(8))) short short8;   // 8 bf16 = 4 VGPRs
typedef __attribute__((ext_vector_type(4))) float f32x4;
typedef __attribute__((ext_vector_type(2))) float f32x2;

#define LRELU_SLOPE 0.2f
#define BPB 32        // blocks per XCD bin for multisplit
#define MAXPER 13000  // max dst-keys per bin that fit the LDS histogram (52 KB)
#define WSTAGE 64     // staged (w,s) slots per row in gather LDS producer phase

__device__ inline float bfbits(u32 hi) { union { u32 i; float f; } v; v.i = hi; return v.f; }
__device__ inline float bflo(u32 w) { return bfbits(w << 16); }
__device__ inline float bfhi(u32 w) { return bfbits(w & 0xFFFF0000u); }
__device__ inline float bf2f(u16 s) { return bfbits(((u32)s) << 16); }
__device__ inline u16 f2bf(float f) {
  union { float f; u32 i; } v; v.f = f;
  u32 r = v.i + 0x7FFFu + ((v.i >> 16) & 1u); // round-to-nearest-even
  return (u16)(r >> 16);
}
__device__ inline f32x2 up2(u32 w) { return (f32x2){bflo(w), bfhi(w)}; }

// bijective XCD swizzle (m204 form; valid for any nwg)
__device__ inline int xcd_swz(int orig, int nwg) {
  int xcd = orig & 7, idx = orig >> 3;
  int q = nwg >> 3, r = nwg & 7;
  return (xcd < r ? xcd * (q + 1) : r * (q + 1) + (xcd - r) * q) + idx;
}

// ------------------------------------------------ fused dtype-sniff + params + gcnt clear
// pf: [0,4096) W row-major, [4096,4160) att_src, [4160,4224) att_dst, [4224,4288) bias
__global__ void dp_kernel(const u32* __restrict__ g, int nwords, int* __restrict__ mode,
                          const void* __restrict__ W, const void* __restrict__ as,
                          const void* __restrict__ ad, const void* __restrict__ bs,
                          float* __restrict__ pf, u16* __restrict__ wfrag,
                          int* __restrict__ gcnt) {
  __shared__ int cnt;
  if (threadIdx.x == 0) cnt = 0;
  if (threadIdx.x < 8) gcnt[threadIdx.x] = 0;
  __syncthreads();
  int c = 0;
  for (int i = threadIdx.x; i < nwords; i += 256) {
    u32 e = g[i] & 0x7F80u;
    if (e >= 0x3000u && e <= 0x4180u) c++;
  }
  atomicAdd(&cnt, c);
  __syncthreads();
  int md = (2 * cnt > nwords) ? 1 : 0;
  if (threadIdx.x == 0) *mode = md;

  for (int i = threadIdx.x; i < 4288; i += 256) {
    const void* p; int j;
    if (i < 4096)      { p = W;  j = i; }
    else if (i < 4160) { p = as; j = i - 4096; }
    else if (i < 4224) { p = ad; j = i - 4160; }
    else               { p = bs; j = i - 4224; }
    pf[i] = md ? bf2f(((const u16*)p)[j]) : ((const float*)p)[j];
  }
  __syncthreads();
  for (int i = threadIdx.x; i < 4096; i += 256) {
    int f = i >> 9, lane = (i >> 3) & 63, j = i & 7;
    int cc = f >> 1, t = f & 1;
    int k = 32 * t + 8 * (lane >> 4) + j;
    int n = 16 * cc + (lane & 15);
    wfrag[i] = f2bf(pf[k * 64 + n]);
  }
}

// ------------------------------------------------ CSR phase-1 body (binning)
__device__ void binA_body(const int* __restrict__ src, const int* __restrict__ dst,
                          int* __restrict__ gcnt, uint2* __restrict__ binned,
                          int E, int nper, int cap, int bid) {
  __shared__ int lcnt[8], lbase[8], lcur[8];
  const int K = 8;
  int tile0 = bid * (256 * K);
  int t = threadIdx.x;
  if (t < 8) { lcnt[t] = 0; lcur[t] = 0; }
  __syncthreads();
  int dv[K], sv[K], bv[K];
#pragma unroll
  for (int j = 0; j < K; ++j) {
    int idx = tile0 + j * 256 + t;
    bool ok = idx < E;
    int d = ok ? __builtin_nontemporal_load(&dst[idx]) : 0;
    int s = ok ? __builtin_nontemporal_load(&src[idx]) : 0;
    int b = -1;
    if (ok) {
      b = (d >= 4 * nper) ? 4 : 0;
      if (d >= (b + 2) * nper) b += 2;
      if (d >= (b + 1) * nper) b += 1;
      atomicAdd(&lcnt[b], 1);
    }
    dv[j] = d; sv[j] = s; bv[j] = b;
  }
  __syncthreads();
  if (t < 8) lbase[t] = atomicAdd(&gcnt[t], lcnt[t]);
  __syncthreads();
#pragma unroll
  for (int j = 0; j < K; ++j) {
    int b = bv[j];
    if (b >= 0) {
      int slot = lbase[b] + atomicAdd(&lcur[b], 1);
      if (slot < cap) binned[(size_t)b * cap + slot] = make_uint2((u32)sv[j], (u32)dv[j]);
    }
  }
}

// ------------------------------------------------ layer-0 projection body (reads g)
// Also inits dummy rows for BOTH h buffers + a_src sentinels (padded-CSR).
__device__ void proj0_body(const void* __restrict__ graw, const int* __restrict__ mode,
                           const u16* __restrict__ wfrag, const float* __restrict__ pf,
                           u16* __restrict__ h0, u16* __restrict__ h1,
                           float* __restrict__ as0, float* __restrict__ as1,
                           float* __restrict__ ad0, int N, int bid, int pblocks) {
  if (bid == 0) {
    if (threadIdx.x < 32)       ((u32*)(h0 + (size_t)N * 64))[threadIdx.x] = 0u;
    else if (threadIdx.x < 64)  ((u32*)(h1 + (size_t)N * 64))[threadIdx.x - 32] = 0u;
    else if (threadIdx.x == 64) as0[N] = -1e30f;
    else if (threadIdx.x == 65) as1[N] = -1e30f;
  }
  int lane = threadIdx.x & 63;
  int quad = lane >> 4, m = lane & 15;
  int wtile = (int)(((size_t)bid * 256 + threadIdx.x) >> 6);
  int ntiles = (N + 15) >> 4;
  int nwaves = pblocks * 4;

  int md = *mode;
  bool f32in = (md == 0);

  short8 bfrag[8];
#pragma unroll
  for (int f = 0; f < 8; ++f)
    bfrag[f] = *(const short8*)(wfrag + f * 512 + lane * 8);
  float asv[4], adv[4];
#pragma unroll
  for (int c = 0; c < 4; ++c) {
    asv[c] = pf[4096 + 16 * c + m];
    adv[c] = pf[4160 + 16 * c + m];
  }

  for (int tile = wtile; tile < ntiles; tile += nwaves) {
    int row0 = tile << 4;
    int rl = row0 + m; if (rl > N - 1) rl = N - 1;
    short8 a0, a1;
    if (f32in) {
      const float* xr = (const float*)graw + (size_t)rl * 64 + 8 * quad;
      float4 f0 = *(const float4*)(xr);
      float4 f1 = *(const float4*)(xr + 4);
      float4 f2 = *(const float4*)(xr + 32);
      float4 f3 = *(const float4*)(xr + 36);
      a0[0] = (short)f2bf(f0.x); a0[1] = (short)f2bf(f0.y);
      a0[2] = (short)f2bf(f0.z); a0[3] = (short)f2bf(f0.w);
      a0[4] = (short)f2bf(f1.x); a0[5] = (short)f2bf(f1.y);
      a0[6] = (short)f2bf(f1.z); a0[7] = (short)f2bf(f1.w);
      a1[0] = (short)f2bf(f2.x); a1[1] = (short)f2bf(f2.y);
      a1[2] = (short)f2bf(f2.z); a1[3] = (short)f2bf(f2.w);
      a1[4] = (short)f2bf(f3.x); a1[5] = (short)f2bf(f3.y);
      a1[6] = (short)f2bf(f3.z); a1[7] = (short)f2bf(f3.w);
    } else {
      const u16* xr = (const u16*)graw + (size_t)rl * 64 + 8 * quad;
      a0 = *(const short8*)(xr);
      a1 = *(const short8*)(xr + 32);
    }

    f32x4 acc[4];
#pragma unroll
    for (int c = 0; c < 4; ++c) {
      f32x4 z = {0.f, 0.f, 0.f, 0.f};
      z = __builtin_amdgcn_mfma_f32_16x16x32_bf16(a0, bfrag[2 * c + 0], z, 0, 0, 0);
      z = __builtin_amdgcn_mfma_f32_16x16x32_bf16(a1, bfrag[2 * c + 1], z, 0, 0, 0);
      acc[c] = z;
    }

#pragma unroll
    for (int r = 0; r < 4; ++r) {
      int row = row0 + 4 * quad + r;
      float v0 = acc[0][r], v1 = acc[1][r], v2 = acc[2][r], v3 = acc[3][r];
      if (row < N) {
        u16* hr = h0 + (size_t)row * 64 + m;
        hr[0]  = f2bf(v0);
        hr[16] = f2bf(v1);
        hr[32] = f2bf(v2);
        hr[48] = f2bf(v3);
      }
      float s1 = v0 * asv[0] + v1 * asv[1] + v2 * asv[2] + v3 * asv[3];
      float s2 = v0 * adv[0] + v1 * adv[1] + v2 * adv[2] + v3 * adv[3];
#pragma unroll
      for (int msk = 1; msk <= 8; msk <<= 1) {
        s1 += __shfl_xor(s1, msk, 64);
        s2 += __shfl_xor(s2, msk, 64);
      }
      if (m == 0 && row < N) { as0[row] = s1; ad0[row] = s2; }
    }
  }
}

// fat kernel: blocks [0,abl) run binA, blocks [abl,..) run proj0 concurrently.
__global__ void __launch_bounds__(256) fatBP_kernel(
    const int* __restrict__ src, const int* __restrict__ dst, int* __restrict__ gcnt,
    uint2* __restrict__ binned, int E, int nper, int cap, int abl,
    const void* __restrict__ graw, const int* __restrict__ mode,
    const u16* __restrict__ wfrag, const float* __restrict__ pf,
    u16* __restrict__ h0, u16* __restrict__ h1,
    float* __restrict__ as0, float* __restrict__ as1,
    float* __restrict__ ad0, int N) {
  if ((int)blockIdx.x < abl) {
    binA_body(src, dst, gcnt, binned, E, nper, cap, (int)blockIdx.x);
  } else {
    proj0_body(graw, mode, wfrag, pf, h0, h1, as0, as1, ad0, N,
               (int)blockIdx.x - abl, (int)gridDim.x - abl);
  }
}

// standalone wrappers (fallback path)
__global__ void __launch_bounds__(256) binA_kernel(
    const int* __restrict__ src, const int* __restrict__ dst, int* __restrict__ gcnt,
    uint2* __restrict__ binned, int E, int nper, int cap) {
  binA_body(src, dst, gcnt, binned, E, nper, cap, (int)blockIdx.x);
}
__global__ void __launch_bounds__(256) proj0_kernel(
    const void* __restrict__ graw, const int* __restrict__ mode,
    const u16* __restrict__ wfrag, const float* __restrict__ pf,
    u16* __restrict__ h0, u16* __restrict__ h1,
    float* __restrict__ as0, float* __restrict__ as1,
    float* __restrict__ ad0, int N) {
  proj0_body(graw, mode, wfrag, pf, h0, h1, as0, as1, ad0, N,
             (int)blockIdx.x, (int)gridDim.x);
}

// Phase 2 (multisplit): per-(bin,chunk) LDS histogram -> coalesced slice stores.
__global__ void __launch_bounds__(256) histA_kernel(
    const uint2* __restrict__ binned, const int* __restrict__ gcnt,
    u32* __restrict__ slices, int nper, int cap) {
  __shared__ u32 cnt_lds[MAXPER];
  int b = blockIdx.x & 7;
  int j = blockIdx.x >> 3;
  int cnt = gcnt[b]; if (cnt > cap) cnt = cap;
  int chunk = (cnt + BPB - 1) / BPB;
  int begin = j * chunk;
  int endc = begin + chunk; if (endc > cnt) endc = cnt;
  for (int k = threadIdx.x; k < nper; k += 256) cnt_lds[k] = 0;
  __syncthreads();
  const uint2* reg = binned + (size_t)b * cap;
  int kbase = b * nper;
  for (int i = begin + threadIdx.x; i < endc; i += 256)
    atomicAdd(&cnt_lds[(int)reg[i].y - kbase], 1u);
  __syncthreads();
  u32* out = slices + (size_t)(b * BPB + j) * nper;
  for (int k = threadIdx.x; k < nper; k += 256) out[k] = cnt_lds[k];
}

// Phase 3: per-key PADDED degree (round up to 8) from slices + block inclusive scan.
__global__ void scan1f_kernel(const u32* __restrict__ slices, int* __restrict__ row_off,
                              int* __restrict__ partials, int nper, int N) {
  __shared__ int smem[1024];
  int t = threadIdx.x;
  int idx = blockIdx.x * 1024 + t;
  int v = 0;
  if (idx < N) {
    int b = idx / nper;
    int kk = idx - b * nper;
    const u32* s = slices + (size_t)b * BPB * nper + kk;
    u32 tt = 0;
#pragma unroll 8
    for (int j = 0; j < BPB; ++j) tt += s[(size_t)j * nper];
    v = (int)((tt + 7u) & ~7u);   // padded degree
  }
  smem[t] = v;
  __syncthreads();
  for (int off = 1; off < 1024; off <<= 1) {
    int u = (t >= off) ? smem[t - off] : 0;
    __syncthreads();
    smem[t] += u;
    __syncthreads();
  }
  if (idx < N) row_off[idx + 1] = smem[t];
  if (t == 1023) partials[blockIdx.x] = smem[t];
}

// Phase 4+5 (fused): finalize padded row_off, slices -> per-chunk bases, pad fill.
__global__ void scan3c_kernel(int* __restrict__ row_off, const int* __restrict__ partials,
                              int P, u32* __restrict__ slices, int* __restrict__ csr_src,
                              int nper, int N, int dummy) {
  __shared__ int smem[1024];
  int t = threadIdx.x;
  int pv = (t < P) ? partials[t] : 0;
  smem[t] = pv;
  __syncthreads();
  for (int off = 1; off < 1024; off <<= 1) {
    int u = (t >= off) ? smem[t - off] : 0;
    __syncthreads();
    smem[t] += u;
    __syncthreads();
  }
  int blk = blockIdx.x;
  int prefix = (blk > 0) ? smem[blk - 1] : 0;
  int idx = blk * 1024 + t;
  if (idx == 0) row_off[0] = 0;
  if (idx < N) {
    int vend = row_off[idx + 1] + prefix;   // padded inclusive end
    row_off[idx + 1] = vend;
    int b = idx / nper;
    int kk = idx - b * nper;
    u32* s = slices + (size_t)b * BPB * nper + kk;
    u32 tv[BPB];
    u32 deg = 0;
#pragma unroll
    for (int j = 0; j < BPB; ++j) { tv[j] = s[(size_t)j * nper]; deg += tv[j]; }
    u32 pdeg = (deg + 7u) & ~7u;
    u32 run = (u32)vend - pdeg;             // padded row start
#pragma unroll
    for (int j = 0; j < BPB; ++j) { s[(size_t)j * nper] = run; run += tv[j]; }
    for (u32 p = run; p < (u32)vend; ++p) csr_src[p] = dummy;  // pad fill
  }
}

// Phase 6: scatter with LDS-only atomics (exact windows known), plain csr stores.
__global__ void __launch_bounds__(256) scatterB_kernel(
    const uint2* __restrict__ binned, const int* __restrict__ gcnt,
    const u32* __restrict__ slices, int* __restrict__ csr_src, int nper, int cap) {
  __shared__ u32 base_lds[MAXPER];
  int b = blockIdx.x & 7;
  int j = blockIdx.x >> 3;
  int cnt = gcnt[b]; if (cnt > cap) cnt = cap;
  int chunk = (cnt + BPB - 1) / BPB;
  int begin = j * chunk;
  int endc = begin + chunk; if (endc > cnt) endc = cnt;
  const u32* s = slices + (size_t)(b * BPB + j) * nper;
  for (int k = threadIdx.x; k < nper; k += 256) base_lds[k] = s[k];
  __syncthreads();
  const uint2* reg = binned + (size_t)b * cap;
  int kbase = b * nper;
  for (int i = begin + threadIdx.x; i < endc; i += 256) {
    uint2 r = reg[i];
    u32 p = atomicAdd(&base_lds[(int)r.y - kbase], 1u);
    csr_src[p] = (int)r.x;
  }
}

// ------------------------------------------------ fallback CSR (nper > MAXPER only)
__global__ void hist_local_kernel(const uint2* __restrict__ binned, const int* __restrict__ gcnt,
                                  int* __restrict__ deg, int cap) {
  int b = blockIdx.x & 7;
  int vb = blockIdx.x >> 3, nvb = gridDim.x >> 3;
  int cnt = gcnt[b]; if (cnt > cap) cnt = cap;
  const uint2* reg = binned + (size_t)b * cap;
  for (int i = vb * blockDim.x + threadIdx.x; i < cnt; i += nvb * blockDim.x)
    atomicAdd(&deg[reg[i].y], 1);
}

__global__ void scatter_local_kernel(const uint2* __restrict__ binned, const int* __restrict__ gcnt,
                                     int* __restrict__ cursor, int* __restrict__ csr_src, int cap) {
  int b = blockIdx.x & 7;
  int vb = blockIdx.x >> 3, nvb = gridDim.x >> 3;
  int cnt = gcnt[b]; if (cnt > cap) cnt = cap;
  const uint2* reg = binned + (size_t)b * cap;
  for (int i = vb * blockDim.x + threadIdx.x; i < cnt; i += nvb * blockDim.x) {
    uint2 r = reg[i];
    int p = atomicAdd(&cursor[r.y], 1);
    csr_src[p] = (int)r.x;
  }
}

__global__ void scan1_kernel(const int* __restrict__ deg, int* __restrict__ row_off,
                             int* __restrict__ partials, int N) {
  __shared__ int smem[1024];
  int t = threadIdx.x;
  int idx = blockIdx.x * 1024 + t;
  int v = (idx < N) ? (int)(((u32)deg[idx] + 7u) & ~7u) : 0;  // padded
  smem[t] = v;
  __syncthreads();
  for (int off = 1; off < 1024; off <<= 1) {
    int u = (t >= off) ? smem[t - off] : 0;
    __syncthreads();
    smem[t] += u;
    __syncthreads();
  }
  if (idx < N) row_off[idx + 1] = smem[t];
  if (t == 1023) partials[blockIdx.x] = smem[t];
}

__global__ void scan2_kernel(int* __restrict__ partials, int P) {
  __shared__ int smem[1024];
  int t = threadIdx.x;
  int v = (t < P) ? partials[t] : 0;
  smem[t] = v;
  __syncthreads();
  for (int off = 1; off < 1024; off <<= 1) {
    int u = (t >= off) ? smem[t - off] : 0;
    __syncthreads();
    smem[t] += u;
    __syncthreads();
  }
  if (t < P) partials[t] = smem[t];
}

__global__ void scan3_kernel(int* __restrict__ row_off, const int* __restrict__ partials,
                             int* __restrict__ cursor, int N) {
  int b = blockIdx.x;
  int idx = b * 1024 + threadIdx.x;
  if (idx < N) {
    int v = row_off[idx + 1] + ((b > 0) ? partials[b - 1] : 0);
    row_off[idx + 1] = v;
    if (idx + 1 < N) cursor[idx + 1] = v;
  }
  if (idx == 0) { row_off[0] = 0; cursor[0] = 0; }
}

__global__ void padC_kernel(const int* __restrict__ row_off, const int* __restrict__ cursor,
                            int* __restrict__ csr_src, int N, int dummy) {
  int i = blockIdx.x * blockDim.x + threadIdx.x;
  if (i >= N) return;
  int e = row_off[i + 1];
  for (int p = cursor[i]; p < e; ++p) csr_src[p] = dummy;
}

// ------------------------------------------------ fused gather_k + proj_{k+1}
// Two-phase gather: PHASE 1 stages (w,s) per edge into LDS -- one a_src load +
// one lrelu/exp PER EDGE (16 producer threads per row, coalesced csr reads) --
// then PHASE 2 runs the proven consumer loop reading (w,s) via ds_read_b64
// (shorter dep chain than the old global csr load). Slots >= WSTAGE (rare
// hubs) fall back to the original direct body.
__global__ void __launch_bounds__(256) fusedFG_kernel(
    const u16* __restrict__ hin, const float* __restrict__ asi,
    const float* __restrict__ adi, u16* __restrict__ hout,
    float* __restrict__ aso, float* __restrict__ ado,
    const int* __restrict__ row_off, const int* __restrict__ csr_src,
    const float* __restrict__ pf, const u16* __restrict__ wfrag, int N) {
  __shared__ u16 xs[16][72];            // staged tile, row-padded for LDS banks
  __shared__ float sred[2][16][4];      // a partials [sel][row][wave]
  __shared__ uint2 lwP[16][WSTAGE + 1]; // staged (w,s) per row (+1 pad for banks)

  int tid = threadIdx.x;
  int lane = tid & 63;
  int w = tid >> 6;            // wave 0..3 = feature block (proj) / node quad (gather)
  int quad = lane >> 4, m = lane & 15;
  int grp = lane >> 4;         // gather: dst sub-group 0..3
  int eg = (lane >> 3) & 1;    // gather: edge parity
  int fg = lane & 7;           // gather: feature octet
  int tile = xcd_swz((int)blockIdx.x, (int)gridDim.x);
  int row_in = w * 4 + grp;
  int i = tile * 16 + row_in;
  bool valid = i < N;

  short8 bf0 = *(const short8*)(wfrag + (2 * w + 0) * 512 + lane * 8);
  short8 bf1 = *(const short8*)(wfrag + (2 * w + 1) * 512 + lane * 8);
  float asw = pf[4096 + 16 * w + m];
  float adw = pf[4160 + 16 * w + m];

  // -------- PHASE 1: producer (16 threads/row, one weight per edge)
  {
    int pr = tid >> 4, pl = tid & 15;
    int ir = tile * 16 + pr;
    if (ir < N) {
      int rb = row_off[ir];
      int lim = row_off[ir + 1] - rb;
      if (lim > WSTAGE) lim = WSTAGE;
      float adv_r = adi[ir];
      for (int j = pl; j < lim; j += 16) {
        int s = csr_src[rb + j];
        float a = asi[s];
        float t = a + adv_r;
        t = (t > 0.f) ? t : LRELU_SLOPE * t;
        float wv = __expf(fminf(t, 60.f));   // dummy slots: exp(-2e29)==0 exactly
        lwP[pr][j] = make_uint2(__float_as_uint(wv), (u32)s);
      }
    }
  }
  __syncthreads();

  int beg = 0, end = 0;
  float advv = 0.f;
  if (valid) { beg = row_off[i]; end = row_off[i + 1]; advv = adi[i]; }

  f32x2 acc0 = {0.f, 0.f}, acc1 = {0.f, 0.f}, acc2 = {0.f, 0.f}, acc3 = {0.f, 0.f};
  float den = 0.f;

  // -------- PHASE 2: consumer over staged slots
  int pd = end - beg;
  int lim = pd < WSTAGE ? pd : WSTAGE;
  for (int o = 0; o < lim; o += 8) {
    int j = o + eg;
    uint2 pA = lwP[row_in][j];
    uint2 pB = lwP[row_in][j + 2];
    uint2 pC = lwP[row_in][j + 4];
    uint2 pD = lwP[row_in][j + 6];
    float wA = __uint_as_float(pA.x); int sA = (int)pA.y;
    float wB = __uint_as_float(pB.x); int sB = (int)pB.y;
    float wC = __uint_as_float(pC.x); int sC = (int)pC.y;
    float wD = __uint_as_float(pD.x); int sD = (int)pD.y;
    uint4 hA = ((const uint4*)(hin + (size_t)sA * 64))[fg];
    uint4 hB = ((const uint4*)(hin + (size_t)sB * 64))[fg];
    uint4 hC = ((const uint4*)(hin + (size_t)sC * 64))[fg];
    uint4 hD = ((const uint4*)(hin + (size_t)sD * 64))[fg];

    den += (wA + wB) + (wC + wD);
    f32x2 wA2 = {wA, wA}, wB2 = {wB, wB}, wC2 = {wC, wC}, wD2 = {wD, wD};
    acc0 += wA2 * up2(hA.x); acc0 += wB2 * up2(hB.x);
    acc0 += wC2 * up2(hC.x); acc0 += wD2 * up2(hD.x);
    acc1 += wA2 * up2(hA.y); acc1 += wB2 * up2(hB.y);
    acc1 += wC2 * up2(hC.y); acc1 += wD2 * up2(hD.y);
    acc2 += wA2 * up2(hA.z); acc2 += wB2 * up2(hB.z);
    acc2 += wC2 * up2(hC.z); acc2 += wD2 * up2(hD.z);
    acc3 += wA2 * up2(hA.w); acc3 += wB2 * up2(hB.w);
    acc3 += wC2 * up2(hC.w); acc3 += wD2 * up2(hD.w);
  }
  // rare hub fallback: direct loads for slots >= WSTAGE (original proven body)
  for (int b0 = beg + WSTAGE; b0 < end; b0 += 8) {
    int eA = b0 + eg;
    int sA = csr_src[eA];
    int sB = csr_src[eA + 2];
    int sC = csr_src[eA + 4];
    int sD = csr_src[eA + 6];
    float aA = asi[sA];
    float aB = asi[sB];
    float aC = asi[sC];
    float aD = asi[sD];
    uint4 hA = ((const uint4*)(hin + (size_t)sA * 64))[fg];
    uint4 hB = ((const uint4*)(hin + (size_t)sB * 64))[fg];
    uint4 hC = ((const uint4*)(hin + (size_t)sC * 64))[fg];
    uint4 hD = ((const uint4*)(hin + (size_t)sD * 64))[fg];
    float tA = aA + advv; tA = (tA > 0.f) ? tA : LRELU_SLOPE * tA;
    float tB = aB + advv; tB = (tB > 0.f) ? tB : LRELU_SLOPE * tB;
    float tC = aC + advv; tC = (tC > 0.f) ? tC : LRELU_SLOPE * tC;
    float tD = aD + advv; tD = (tD > 0.f) ? tD : LRELU_SLOPE * tD;
    float wA = __expf(fminf(tA, 60.f));
    float wB = __expf(fminf(tB, 60.f));
    float wC = __expf(fminf(tC, 60.f));
    float wD = __expf(fminf(tD, 60.f));
    den += (wA + wB) + (wC + wD);
    f32x2 wA2 = {wA, wA}, wB2 = {wB, wB}, wC2 = {wC, wC}, wD2 = {wD, wD};
    acc0 += wA2 * up2(hA.x); acc0 += wB2 * up2(hB.x);
    acc0 += wC2 * up2(hC.x); acc0 += wD2 * up2(hD.x);
    acc1 += wA2 * up2(hA.y); acc1 += wB2 * up2(hB.y);
    acc1 += wC2 * up2(hC.y); acc1 += wD2 * up2(hD.y);
    acc2 += wA2 * up2(hA.z); acc2 += wB2 * up2(hB.z);
    acc2 += wC2 * up2(hC.z); acc2 += wD2 * up2(hD.z);
    acc3 += wA2 * up2(hA.w); acc3 += wB2 * up2(hB.w);
    acc3 += wC2 * up2(hC.w); acc3 += wD2 * up2(hD.w);
  }

  den += __shfl_xor(den, 8, 64);
#pragma unroll
  for (int c = 0; c < 2; ++c) {
    acc0[c] += __shfl_xor(acc0[c], 8, 64);
    acc1[c] += __shfl_xor(acc1[c], 8, 64);
    acc2[c] += __shfl_xor(acc2[c], 8, 64);
    acc3[c] += __shfl_xor(acc3[c], 8, 64);
  }
  float inv = (den > 0.f) ? 1.f / den : 0.f;
  float oa[8] = {acc0[0], acc0[1], acc1[0], acc1[1],
                 acc2[0], acc2[1], acc3[0], acc3[1]};

  // stage biased bf16 row into LDS for the fused proj
  if (!eg) {
    u32 o[4];
    if (valid) {
#pragma unroll
      for (int j = 0; j < 4; ++j) {
        float v0 = oa[2 * j]     * inv + pf[4224 + 8 * fg + 2 * j];
        float v1 = oa[2 * j + 1] * inv + pf[4224 + 8 * fg + 2 * j + 1];
        o[j] = (u32)f2bf(v0) | ((u32)f2bf(v1) << 16);
      }
    } else {
      o[0] = o[1] = o[2] = o[3] = 0u;
    }
    *(uint4*)&xs[row_in][fg * 8] = make_uint4(o[0], o[1], o[2], o[3]);
  }
  __syncthreads();

  // proj: wave w computes feature block w for all 16 rows
  short8 a0 = *(const short8*)&xs[m][8 * quad];
  short8 a1 = *(const short8*)&xs[m][32 + 8 * quad];
  f32x4 z = {0.f, 0.f, 0.f, 0.f};
  z = __builtin_amdgcn_mfma_f32_16x16x32_bf16(a0, bf0, z, 0, 0, 0);
  z = __builtin_amdgcn_mfma_f32_16x16x32_bf16(a1, bf1, z, 0, 0, 0);
#pragma unroll
  for (int r = 0; r < 4; ++r) {
    int row = tile * 16 + 4 * quad + r;
    if (row < N) hout[(size_t)row * 64 + 16 * w + m] = f2bf(z[r]);
    float s1 = z[r] * asw, s2 = z[r] * adw;
#pragma unroll
    for (int msk = 1; msk <= 8; msk <<= 1) {
      s1 += __shfl_xor(s1, msk, 64);
      s2 += __shfl_xor(s2, msk, 64);
    }
    if (m == 0) { sred[0][4 * quad + r][w] = s1; sred[1][4 * quad + r][w] = s2; }
  }
  __syncthreads();
  if (tid < 32) {
    int row = tid & 15, sel = tid >> 4;
    float v = sred[sel][row][0] + sred[sel][row][1] + sred[sel][row][2] + sred[sel][row][3];
    int gr = tile * 16 + row;
    if (gr < N) (sel ? ado : aso)[gr] = v;
  }
}

// ------------------------------------------------ final gather -> d_out
// Same two-phase structure as fusedFG.
__global__ void __launch_bounds__(256) gatherL_kernel(
    const u16* __restrict__ h, const float* __restrict__ a_src,
    const float* __restrict__ a_dst, const int* __restrict__ row_off,
    const int* __restrict__ csr_src, const float* __restrict__ pf,
    void* __restrict__ dout, int N, const int* __restrict__ mode) {
  __shared__ uint2 lwP[16][WSTAGE + 1];
  int tid = threadIdx.x;
  int lane = tid & 63;
  int grp = lane >> 4;
  int eg  = (lane >> 3) & 1;
  int fg  = lane & 7;
  int w   = tid >> 6;
  int tile = xcd_swz((int)blockIdx.x, (int)gridDim.x);
  int row_in = w * 4 + grp;
  int i = tile * 16 + row_in;
  bool valid = i < N;

  // PHASE 1: producer
  {
    int pr = tid >> 4, pl = tid & 15;
    int ir = tile * 16 + pr;
    if (ir < N) {
      int rb = row_off[ir];
      int lim = row_off[ir + 1] - rb;
      if (lim > WSTAGE) lim = WSTAGE;
      float adv_r = a_dst[ir];
      for (int j = pl; j < lim; j += 16) {
        int s = csr_src[rb + j];
        float a = a_src[s];
        float t = a + adv_r;
        t = (t > 0.f) ? t : LRELU_SLOPE * t;
        float wv = __expf(fminf(t, 60.f));
        lwP[pr][j] = make_uint2(__float_as_uint(wv), (u32)s);
      }
    }
  }
  __syncthreads();

  int beg = 0, end = 0;
  float adv = 0.f;
  if (valid) {
    beg = row_off[i];
    end = row_off[i + 1];
    adv = a_dst[i];
  }

  f32x2 acc0 = {0.f, 0.f}, acc1 = {0.f, 0.f}, acc2 = {0.f, 0.f}, acc3 = {0.f, 0.f};
  float den = 0.f;

  int pd = end - beg;
  int lim = pd < WSTAGE ? pd : WSTAGE;
  for (int o = 0; o < lim; o += 8) {
    int j = o + eg;
    uint2 pA = lwP[row_in][j];
    uint2 pB = lwP[row_in][j + 2];
    uint2 pC = lwP[row_in][j + 4];
    uint2 pD = lwP[row_in][j + 6];
    float wA = __uint_as_float(pA.x); int sA = (int)pA.y;
    float wB = __uint_as_float(pB.x); int sB = (int)pB.y;
    float wC = __uint_as_float(pC.x); int sC = (int)pC.y;
    float wD = __uint_as_float(pD.x); int sD = (int)pD.y;
    uint4 hA = ((const uint4*)(h + (size_t)sA * 64))[fg];
    uint4 hB = ((const uint4*)(h + (size_t)sB * 64))[fg];
    uint4 hC = ((const uint4*)(h + (size_t)sC * 64))[fg];
    uint4 hD = ((const uint4*)(h + (size_t)sD * 64))[fg];

    den += (wA + wB) + (wC + wD);
    f32x2 wA2 = {wA, wA}, wB2 = {wB, wB}, wC2 = {wC, wC}, wD2 = {wD, wD};
    acc0 += wA2 * up2(hA.x); acc0 += wB2 * up2(hB.x);
    acc0 += wC2 * up2(hC.x); acc0 += wD2 * up2(hD.x);
    acc1 += wA2 * up2(hA.y); acc1 += wB2 * up2(hB.y);
    acc1 += wC2 * up2(hC.y); acc1 += wD2 * up2(hD.y);
    acc2 += wA2 * up2(hA.z); acc2 += wB2 * up2(hB.z);
    acc2 += wC2 * up2(hC.z); acc2 += wD2 * up2(hD.z);
    acc3 += wA2 * up2(hA.w); acc3 += wB2 * up2(hB.w);
    acc3 += wC2 * up2(hC.w); acc3 += wD2 * up2(hD.w);
  }
  for (int b0 = beg + WSTAGE; b0 < end; b0 += 8) {
    int eA = b0 + eg;
    int sA = csr_src[eA];
    int sB = csr_src[eA + 2];
    int sC = csr_src[eA + 4];
    int sD = csr_src[eA + 6];
    float aA = a_src[sA];
    float aB = a_src[sB];
    float aC = a_src[sC];
    float aD = a_src[sD];
    uint4 hA = ((const uint4*)(h + (size_t)sA * 64))[fg];
    uint4 hB = ((const uint4*)(h + (size_t)sB * 64))[fg];
    uint4 hC = ((const uint4*)(h + (size_t)sC * 64))[fg];
    uint4 hD = ((const uint4*)(h + (size_t)sD * 64))[fg];
    float tA = aA + adv; tA = (tA > 0.f) ? tA : LRELU_SLOPE * tA;
    float tB = aB + adv; tB = (tB > 0.f) ? tB : LRELU_SLOPE * tB;
    float tC = aC + adv; tC = (tC > 0.f) ? tC : LRELU_SLOPE * tC;
    float tD = aD + adv; tD = (tD > 0.f) ? tD : LRELU_SLOPE * tD;
    float wA = __expf(fminf(tA, 60.f));
    float wB = __expf(fminf(tB, 60.f));
    float wC = __expf(fminf(tC, 60.f));
    float wD = __expf(fminf(tD, 60.f));
    den += (wA + wB) + (wC + wD);
    f32x2 wA2 = {wA, wA}, wB2 = {wB, wB}, wC2 = {wC, wC}, wD2 = {wD, wD};
    acc0 += wA2 * up2(hA.x); acc0 += wB2 * up2(hB.x);
    acc0 += wC2 * up2(hC.x); acc0 += wD2 * up2(hD.x);
    acc1 += wA2 * up2(hA.y); acc1 += wB2 * up2(hB.y);
    acc1 += wC2 * up2(hC.y); acc1 += wD2 * up2(hD.y);
    acc2 += wA2 * up2(hA.z); acc2 += wB2 * up2(hB.z);
    acc2 += wC2 * up2(hC.z); acc2 += wD2 * up2(hD.z);
    acc3 += wA2 * up2(hA.w); acc3 += wB2 * up2(hB.w);
    acc3 += wC2 * up2(hC.w); acc3 += wD2 * up2(hD.w);
  }

  den += __shfl_xor(den, 8, 64);
#pragma unroll
  for (int c = 0; c < 2; ++c) {
    acc0[c] += __shfl_xor(acc0[c], 8, 64);
    acc1[c] += __shfl_xor(acc1[c], 8, 64);
    acc2[c] += __shfl_xor(acc2[c], 8, 64);
    acc3[c] += __shfl_xor(acc3[c], 8, 64);
  }
  float inv = (den > 0.f) ? 1.f / den : 0.f;

  if (!valid || eg) return;

  float oa[8] = {acc0[0], acc0[1], acc1[0], acc1[1], acc2[0], acc2[1], acc3[0], acc3[1]};
  if (*mode) {
    u32 o[4];
#pragma unroll
    for (int j = 0; j < 4; ++j) {
      float f0 = oa[2 * j]     * inv + pf[4224 + 8 * fg + 2 * j];
      float f1 = oa[2 * j + 1] * inv + pf[4224 + 8 * fg + 2 * j + 1];
      o[j] = (u32)f2bf(f0) | ((u32)f2bf(f1) << 16);
    }
    *(uint4*)((u16*)dout + (size_t)i * 64 + fg * 8) = make_uint4(o[0], o[1], o[2], o[3]);
  } else {
    float o[8];
#pragma unroll
    for (int j = 0; j < 8; ++j)
      o[j] = oa[j] * inv + pf[4224 + 8 * fg + j];
    float* dp = (float*)dout + (size_t)i * 64 + fg * 8;
    *(float4*)(dp)     = make_float4(o[0], o[1], o[2], o[3]);
    *(float4*)(dp + 4) = make_float4(o[4], o[5], o[6], o[7]);
  }
}

// ------------------------------------------------ launcher
extern "C" void kernel_launch(void* const* d_in, const int* in_sizes, int n_in,
                              void* d_out, int out_size, void* d_ws, size_t ws_size,
                              hipStream_t stream) {
  const void* g     = d_in[0];
  const int*  edge  = (const int*)d_in[1];
  const void* Wp    = d_in[2];
  const void* attsp = d_in[3];
  const void* attdp = d_in[4];
  const void* biasp = d_in[5];

  const int D = 64;
  const int N = in_sizes[0] / D;
  const int E = in_sizes[1] / 2;
  const int* src = edge;
  const int* dst = edge + E;

  int nper = (N + 7) / 8;  // dst ids per XCD bucket
  bool fast_csr = (nper <= MAXPER);

  char* ws = (char*)d_ws;
  size_t off = 0;
  auto alloc = [&](size_t bytes) -> char* {
    char* p = ws + off;
    off += (bytes + 255) & ~size_t(255);
    return p;
  };
  size_t h_bytes = (size_t)(N + 1) * D * sizeof(u16);    // +1 dummy row
  u16*   h0       = (u16*)alloc(h_bytes);
  u16*   h1       = (u16*)alloc(h_bytes);
  u32*   slices   = (u32*)alloc((size_t)8 * BPB * nper * sizeof(u32)); // un-aliased
  float* pf       = (float*)alloc(4288 * sizeof(float));
  u16*   wfrag    = (u16*)alloc(4096 * sizeof(u16));
  float* as0      = (float*)alloc((size_t)(N + 1) * sizeof(float));
  float* as1      = (float*)alloc((size_t)(N + 1) * sizeof(float));
  float* ad0      = (float*)alloc((size_t)N * sizeof(float));
  float* ad1      = (float*)alloc((size_t)N * sizeof(float));
  int*   deg      = (int*)alloc((size_t)N * sizeof(int));
  int*   row_off  = (int*)alloc((size_t)(N + 1) * sizeof(int));
  int*   cursor   = (int*)alloc((size_t)N * sizeof(int));
  int*   csr_src  = (int*)alloc(((size_t)E + 8 * (size_t)N) * sizeof(int)); // padded CSR
  int*   partials = (int*)alloc(1024 * sizeof(int));
  int*   mode     = (int*)alloc(256);
  int*   gcnt     = (int*)alloc(256);
  int    cap      = E / 8 + 16384;                               // per-XCD region capacity
  uint2* binned   = (uint2*)alloc((size_t)8 * cap * sizeof(uint2)); // ~9 MB

  dp_kernel<<<1, 256, 0, stream>>>((const u32*)g, 4096, mode, Wp, attsp, attdp, biasp,
                                   pf, wfrag, gcnt);

  if (!fast_csr) hipMemsetAsync(deg, 0, (size_t)N * sizeof(int), stream);
  int abl = (E + 2047) / 2048;  // 8 edges/thread, 256 threads
  int ntiles = (N + 15) / 16;
  int tblocks = (ntiles + 3) / 4;  // 1 tile/wave for proj0

  int nblk = (N + 1023) / 1024;
  if (fast_csr) {
    // binA || proj0 in one fat kernel (both depend only on dp)
    fatBP_kernel<<<abl + tblocks, 256, 0, stream>>>(
        src, dst, gcnt, binned, E, nper, cap, abl,
        g, mode, wfrag, pf, h0, h1, as0, as1, ad0, N);
    histA_kernel<<<8 * BPB, 256, 0, stream>>>(binned, gcnt, slices, nper, cap);
    scan1f_kernel<<<nblk, 1024, 0, stream>>>(slices, row_off, partials, nper, N);
    scan3c_kernel<<<nblk, 1024, 0, stream>>>(row_off, partials, nblk, slices, csr_src,
                                             nper, N, N);
    scatterB_kernel<<<8 * BPB, 256, 0, stream>>>(binned, gcnt, slices, csr_src, nper, cap);
  } else {
    binA_kernel<<<abl, 256, 0, stream>>>(src, dst, gcnt, binned, E, nper, cap);
    hist_local_kernel<<<1024, 256, 0, stream>>>(binned, gcnt, deg, cap);
    scan1_kernel<<<nblk, 1024, 0, stream>>>(deg, row_off, partials, N);
    scan2_kernel<<<1, 1024, 0, stream>>>(partials, nblk);
    scan3_kernel<<<nblk, 1024, 0, stream>>>(row_off, partials, cursor, N);
    scatter_local_kernel<<<1024, 256, 0, stream>>>(binned, gcnt, cursor, csr_src, cap);
    padC_kernel<<<(N + 255) / 256, 256, 0, stream>>>(row_off, cursor, csr_src, N, N);
    proj0_kernel<<<tblocks, 256, 0, stream>>>(g, mode, wfrag, pf, h0, h1, as0, as1, ad0, N);
  }

  // layers 1..3: fused gather_k + proj_{k+1}, one 16-node tile per block
  fusedFG_kernel<<<ntiles, 256, 0, stream>>>(h0, as0, ad0, h1, as1, ad1,
                                             row_off, csr_src, pf, wfrag, N);
  fusedFG_kernel<<<ntiles, 256, 0, stream>>>(h1, as1, ad1, h0, as0, ad0,
                                             row_off, csr_src, pf, wfrag, N);
  fusedFG_kernel<<<ntiles, 256, 0, stream>>>(h0, as0, ad0, h1, as1, ad1,
                                             row_off, csr_src, pf, wfrag, N);

  // layer 4: final gather -> d_out
  gatherL_kernel<<<ntiles, 256, 0, stream>>>(h1, as1, ad1, row_off, csr_src, pf,
                                             d_out, N, mode);
}

// Round 10
// 260.071 us; speedup vs baseline: 1.0360x; 1.0360x over previous
//
#include <hip/hip_runtime.h>
#include <hip/hip_bf16.h>

typedef unsigned int u32;
typedef unsigned short u16;
typedef unsigned long long u64;
typedef __attribute__((ext_vector_type(8))) short short8;   // 8 bf16 = 4 VGPRs
typedef __attribute__((ext_vector_type(4))) float f32x4;
typedef __attribute__((ext_vector_type(2))) float f32x2;

#define LRELU_SLOPE 0.2f
#define BPB 32        // blocks per XCD bin for multisplit
#define MAXPER 13000  // max dst-keys per bin that fit the LDS histogram (52 KB)

__device__ inline float bfbits(u32 hi) { union { u32 i; float f; } v; v.i = hi; return v.f; }
__device__ inline float bflo(u32 w) { return bfbits(w << 16); }
__device__ inline float bfhi(u32 w) { return bfbits(w & 0xFFFF0000u); }
__device__ inline float bf2f(u16 s) { return bfbits(((u32)s) << 16); }
__device__ inline u16 f2bf(float f) {
  union { float f; u32 i; } v; v.f = f;
  u32 r = v.i + 0x7FFFu + ((v.i >> 16) & 1u); // round-to-nearest-even
  return (u16)(r >> 16);
}
__device__ inline f32x2 up2(u32 w) { return (f32x2){bflo(w), bfhi(w)}; }

// bijective XCD swizzle (m204 form; valid for any nwg)
__device__ inline int xcd_swz(int orig, int nwg) {
  int xcd = orig & 7, idx = orig >> 3;
  int q = nwg >> 3, r = nwg & 7;
  return (xcd < r ? xcd * (q + 1) : r * (q + 1) + (xcd - r) * q) + idx;
}

// ------------------------------------------------ fused dtype-sniff + params + gcnt clear
// pf: [0,4096) W row-major, [4096,4160) att_src, [4160,4224) att_dst, [4224,4288) bias
__global__ void dp_kernel(const u32* __restrict__ g, int nwords, int* __restrict__ mode,
                          const void* __restrict__ W, const void* __restrict__ as,
                          const void* __restrict__ ad, const void* __restrict__ bs,
                          float* __restrict__ pf, u16* __restrict__ wfrag,
                          int* __restrict__ gcnt) {
  __shared__ int cnt;
  if (threadIdx.x == 0) cnt = 0;
  if (threadIdx.x < 8) gcnt[threadIdx.x] = 0;
  __syncthreads();
  int c = 0;
  for (int i = threadIdx.x; i < nwords; i += 256) {
    u32 e = g[i] & 0x7F80u;
    if (e >= 0x3000u && e <= 0x4180u) c++;
  }
  atomicAdd(&cnt, c);
  __syncthreads();
  int md = (2 * cnt > nwords) ? 1 : 0;
  if (threadIdx.x == 0) *mode = md;

  for (int i = threadIdx.x; i < 4288; i += 256) {
    const void* p; int j;
    if (i < 4096)      { p = W;  j = i; }
    else if (i < 4160) { p = as; j = i - 4096; }
    else if (i < 4224) { p = ad; j = i - 4160; }
    else               { p = bs; j = i - 4224; }
    pf[i] = md ? bf2f(((const u16*)p)[j]) : ((const float*)p)[j];
  }
  __syncthreads();
  for (int i = threadIdx.x; i < 4096; i += 256) {
    int f = i >> 9, lane = (i >> 3) & 63, j = i & 7;
    int cc = f >> 1, t = f & 1;
    int k = 32 * t + 8 * (lane >> 4) + j;
    int n = 16 * cc + (lane & 15);
    wfrag[i] = f2bf(pf[k * 64 + n]);
  }
}

// ------------------------------------------------ CSR phase-1 body (binning)
__device__ void binA_body(const int* __restrict__ src, const int* __restrict__ dst,
                          int* __restrict__ gcnt, uint2* __restrict__ binned,
                          int E, int nper, int cap, int bid) {
  __shared__ int lcnt[8], lbase[8], lcur[8];
  const int K = 8;
  int tile0 = bid * (256 * K);
  int t = threadIdx.x;
  if (t < 8) { lcnt[t] = 0; lcur[t] = 0; }
  __syncthreads();
  int dv[K], sv[K], bv[K];
#pragma unroll
  for (int j = 0; j < K; ++j) {
    int idx = tile0 + j * 256 + t;
    bool ok = idx < E;
    int d = ok ? __builtin_nontemporal_load(&dst[idx]) : 0;
    int s = ok ? __builtin_nontemporal_load(&src[idx]) : 0;
    int b = -1;
    if (ok) {
      b = (d >= 4 * nper) ? 4 : 0;
      if (d >= (b + 2) * nper) b += 2;
      if (d >= (b + 1) * nper) b += 1;
      atomicAdd(&lcnt[b], 1);
    }
    dv[j] = d; sv[j] = s; bv[j] = b;
  }
  __syncthreads();
  if (t < 8) lbase[t] = atomicAdd(&gcnt[t], lcnt[t]);
  __syncthreads();
#pragma unroll
  for (int j = 0; j < K; ++j) {
    int b = bv[j];
    if (b >= 0) {
      int slot = lbase[b] + atomicAdd(&lcur[b], 1);
      if (slot < cap) binned[(size_t)b * cap + slot] = make_uint2((u32)sv[j], (u32)dv[j]);
    }
  }
}

// ------------------------------------------------ layer-0 projection body (reads g)
// Also inits dummy rows for BOTH h buffers + a_src sentinels (padded-CSR).
__device__ void proj0_body(const void* __restrict__ graw, const int* __restrict__ mode,
                           const u16* __restrict__ wfrag, const float* __restrict__ pf,
                           u16* __restrict__ h0, u16* __restrict__ h1,
                           float* __restrict__ as0, float* __restrict__ as1,
                           float* __restrict__ ad0, int N, int bid, int pblocks) {
  if (bid == 0) {
    if (threadIdx.x < 32)       ((u32*)(h0 + (size_t)N * 64))[threadIdx.x] = 0u;
    else if (threadIdx.x < 64)  ((u32*)(h1 + (size_t)N * 64))[threadIdx.x - 32] = 0u;
    else if (threadIdx.x == 64) as0[N] = -1e30f;
    else if (threadIdx.x == 65) as1[N] = -1e30f;
  }
  int lane = threadIdx.x & 63;
  int quad = lane >> 4, m = lane & 15;
  int wtile = (int)(((size_t)bid * 256 + threadIdx.x) >> 6);
  int ntiles = (N + 15) >> 4;
  int nwaves = pblocks * 4;

  int md = *mode;
  bool f32in = (md == 0);

  short8 bfrag[8];
#pragma unroll
  for (int f = 0; f < 8; ++f)
    bfrag[f] = *(const short8*)(wfrag + f * 512 + lane * 8);
  float asv[4], adv[4];
#pragma unroll
  for (int c = 0; c < 4; ++c) {
    asv[c] = pf[4096 + 16 * c + m];
    adv[c] = pf[4160 + 16 * c + m];
  }

  for (int tile = wtile; tile < ntiles; tile += nwaves) {
    int row0 = tile << 4;
    int rl = row0 + m; if (rl > N - 1) rl = N - 1;
    short8 a0, a1;
    if (f32in) {
      const float* xr = (const float*)graw + (size_t)rl * 64 + 8 * quad;
      float4 f0 = *(const float4*)(xr);
      float4 f1 = *(const float4*)(xr + 4);
      float4 f2 = *(const float4*)(xr + 32);
      float4 f3 = *(const float4*)(xr + 36);
      a0[0] = (short)f2bf(f0.x); a0[1] = (short)f2bf(f0.y);
      a0[2] = (short)f2bf(f0.z); a0[3] = (short)f2bf(f0.w);
      a0[4] = (short)f2bf(f1.x); a0[5] = (short)f2bf(f1.y);
      a0[6] = (short)f2bf(f1.z); a0[7] = (short)f2bf(f1.w);
      a1[0] = (short)f2bf(f2.x); a1[1] = (short)f2bf(f2.y);
      a1[2] = (short)f2bf(f2.z); a1[3] = (short)f2bf(f2.w);
      a1[4] = (short)f2bf(f3.x); a1[5] = (short)f2bf(f3.y);
      a1[6] = (short)f2bf(f3.z); a1[7] = (short)f2bf(f3.w);
    } else {
      const u16* xr = (const u16*)graw + (size_t)rl * 64 + 8 * quad;
      a0 = *(const short8*)(xr);
      a1 = *(const short8*)(xr + 32);
    }

    f32x4 acc[4];
#pragma unroll
    for (int c = 0; c < 4; ++c) {
      f32x4 z = {0.f, 0.f, 0.f, 0.f};
      z = __builtin_amdgcn_mfma_f32_16x16x32_bf16(a0, bfrag[2 * c + 0], z, 0, 0, 0);
      z = __builtin_amdgcn_mfma_f32_16x16x32_bf16(a1, bfrag[2 * c + 1], z, 0, 0, 0);
      acc[c] = z;
    }

#pragma unroll
    for (int r = 0; r < 4; ++r) {
      int row = row0 + 4 * quad + r;
      float v0 = acc[0][r], v1 = acc[1][r], v2 = acc[2][r], v3 = acc[3][r];
      if (row < N) {
        u16* hr = h0 + (size_t)row * 64 + m;
        hr[0]  = f2bf(v0);
        hr[16] = f2bf(v1);
        hr[32] = f2bf(v2);
        hr[48] = f2bf(v3);
      }
      float s1 = v0 * asv[0] + v1 * asv[1] + v2 * asv[2] + v3 * asv[3];
      float s2 = v0 * adv[0] + v1 * adv[1] + v2 * adv[2] + v3 * adv[3];
#pragma unroll
      for (int msk = 1; msk <= 8; msk <<= 1) {
        s1 += __shfl_xor(s1, msk, 64);
        s2 += __shfl_xor(s2, msk, 64);
      }
      if (m == 0 && row < N) { as0[row] = s1; ad0[row] = s2; }
    }
  }
}

// fat kernel: blocks [0,abl) run binA, blocks [abl,..) run proj0 concurrently.
// (both depend only on dp; h0 no longer aliases slices)
__global__ void __launch_bounds__(256) fatBP_kernel(
    const int* __restrict__ src, const int* __restrict__ dst, int* __restrict__ gcnt,
    uint2* __restrict__ binned, int E, int nper, int cap, int abl,
    const void* __restrict__ graw, const int* __restrict__ mode,
    const u16* __restrict__ wfrag, const float* __restrict__ pf,
    u16* __restrict__ h0, u16* __restrict__ h1,
    float* __restrict__ as0, float* __restrict__ as1,
    float* __restrict__ ad0, int N) {
  if ((int)blockIdx.x < abl) {
    binA_body(src, dst, gcnt, binned, E, nper, cap, (int)blockIdx.x);
  } else {
    proj0_body(graw, mode, wfrag, pf, h0, h1, as0, as1, ad0, N,
               (int)blockIdx.x - abl, (int)gridDim.x - abl);
  }
}

// standalone wrappers (fallback path)
__global__ void __launch_bounds__(256) binA_kernel(
    const int* __restrict__ src, const int* __restrict__ dst, int* __restrict__ gcnt,
    uint2* __restrict__ binned, int E, int nper, int cap) {
  binA_body(src, dst, gcnt, binned, E, nper, cap, (int)blockIdx.x);
}
__global__ void __launch_bounds__(256) proj0_kernel(
    const void* __restrict__ graw, const int* __restrict__ mode,
    const u16* __restrict__ wfrag, const float* __restrict__ pf,
    u16* __restrict__ h0, u16* __restrict__ h1,
    float* __restrict__ as0, float* __restrict__ as1,
    float* __restrict__ ad0, int N) {
  proj0_body(graw, mode, wfrag, pf, h0, h1, as0, as1, ad0, N,
             (int)blockIdx.x, (int)gridDim.x);
}

// Phase 2 (multisplit): per-(bin,chunk) LDS histogram -> coalesced slice stores.
__global__ void __launch_bounds__(256) histA_kernel(
    const uint2* __restrict__ binned, const int* __restrict__ gcnt,
    u32* __restrict__ slices, int nper, int cap) {
  __shared__ u32 cnt_lds[MAXPER];
  int b = blockIdx.x & 7;
  int j = blockIdx.x >> 3;
  int cnt = gcnt[b]; if (cnt > cap) cnt = cap;
  int chunk = (cnt + BPB - 1) / BPB;
  int begin = j * chunk;
  int endc = begin + chunk; if (endc > cnt) endc = cnt;
  for (int k = threadIdx.x; k < nper; k += 256) cnt_lds[k] = 0;
  __syncthreads();
  const uint2* reg = binned + (size_t)b * cap;
  int kbase = b * nper;
  for (int i = begin + threadIdx.x; i < endc; i += 256)
    atomicAdd(&cnt_lds[(int)reg[i].y - kbase], 1u);
  __syncthreads();
  u32* out = slices + (size_t)(b * BPB + j) * nper;
  for (int k = threadIdx.x; k < nper; k += 256) out[k] = cnt_lds[k];
}

// Phase 3: per-key PADDED degree (round up to 8) from slices + block inclusive scan.
__global__ void scan1f_kernel(const u32* __restrict__ slices, int* __restrict__ row_off,
                              int* __restrict__ partials, int nper, int N) {
  __shared__ int smem[1024];
  int t = threadIdx.x;
  int idx = blockIdx.x * 1024 + t;
  int v = 0;
  if (idx < N) {
    int b = idx / nper;
    int kk = idx - b * nper;
    const u32* s = slices + (size_t)b * BPB * nper + kk;
    u32 tt = 0;
#pragma unroll 8
    for (int j = 0; j < BPB; ++j) tt += s[(size_t)j * nper];
    v = (int)((tt + 7u) & ~7u);   // padded degree
  }
  smem[t] = v;
  __syncthreads();
  for (int off = 1; off < 1024; off <<= 1) {
    int u = (t >= off) ? smem[t - off] : 0;
    __syncthreads();
    smem[t] += u;
    __syncthreads();
  }
  if (idx < N) row_off[idx + 1] = smem[t];
  if (t == 1023) partials[blockIdx.x] = smem[t];
}

// Phase 4+5 (fused): finalize padded row_off, slices -> per-chunk bases, pad fill.
__global__ void scan3c_kernel(int* __restrict__ row_off, const int* __restrict__ partials,
                              int P, u32* __restrict__ slices, int* __restrict__ csr_src,
                              int nper, int N, int dummy) {
  __shared__ int smem[1024];
  int t = threadIdx.x;
  int pv = (t < P) ? partials[t] : 0;
  smem[t] = pv;
  __syncthreads();
  for (int off = 1; off < 1024; off <<= 1) {
    int u = (t >= off) ? smem[t - off] : 0;
    __syncthreads();
    smem[t] += u;
    __syncthreads();
  }
  int blk = blockIdx.x;
  int prefix = (blk > 0) ? smem[blk - 1] : 0;
  int idx = blk * 1024 + t;
  if (idx == 0) row_off[0] = 0;
  if (idx < N) {
    int vend = row_off[idx + 1] + prefix;   // padded inclusive end
    row_off[idx + 1] = vend;
    int b = idx / nper;
    int kk = idx - b * nper;
    u32* s = slices + (size_t)b * BPB * nper + kk;
    u32 tv[BPB];
    u32 deg = 0;
#pragma unroll
    for (int j = 0; j < BPB; ++j) { tv[j] = s[(size_t)j * nper]; deg += tv[j]; }
    u32 pdeg = (deg + 7u) & ~7u;
    u32 run = (u32)vend - pdeg;             // padded row start
#pragma unroll
    for (int j = 0; j < BPB; ++j) { s[(size_t)j * nper] = run; run += tv[j]; }
    for (u32 p = run; p < (u32)vend; ++p) csr_src[p] = dummy;  // pad fill
  }
}

// Phase 6: scatter with LDS-only atomics (exact windows known), plain csr stores.
__global__ void __launch_bounds__(256) scatterB_kernel(
    const uint2* __restrict__ binned, const int* __restrict__ gcnt,
    const u32* __restrict__ slices, int* __restrict__ csr_src, int nper, int cap) {
  __shared__ u32 base_lds[MAXPER];
  int b = blockIdx.x & 7;
  int j = blockIdx.x >> 3;
  int cnt = gcnt[b]; if (cnt > cap) cnt = cap;
  int chunk = (cnt + BPB - 1) / BPB;
  int begin = j * chunk;
  int endc = begin + chunk; if (endc > cnt) endc = cnt;
  const u32* s = slices + (size_t)(b * BPB + j) * nper;
  for (int k = threadIdx.x; k < nper; k += 256) base_lds[k] = s[k];
  __syncthreads();
  const uint2* reg = binned + (size_t)b * cap;
  int kbase = b * nper;
  for (int i = begin + threadIdx.x; i < endc; i += 256) {
    uint2 r = reg[i];
    u32 p = atomicAdd(&base_lds[(int)r.y - kbase], 1u);
    csr_src[p] = (int)r.x;
  }
}

// ------------------------------------------------ fallback CSR (nper > MAXPER only)
__global__ void hist_local_kernel(const uint2* __restrict__ binned, const int* __restrict__ gcnt,
                                  int* __restrict__ deg, int cap) {
  int b = blockIdx.x & 7;
  int vb = blockIdx.x >> 3, nvb = gridDim.x >> 3;
  int cnt = gcnt[b]; if (cnt > cap) cnt = cap;
  const uint2* reg = binned + (size_t)b * cap;
  for (int i = vb * blockDim.x + threadIdx.x; i < cnt; i += nvb * blockDim.x)
    atomicAdd(&deg[reg[i].y], 1);
}

__global__ void scatter_local_kernel(const uint2* __restrict__ binned, const int* __restrict__ gcnt,
                                     int* __restrict__ cursor, int* __restrict__ csr_src, int cap) {
  int b = blockIdx.x & 7;
  int vb = blockIdx.x >> 3, nvb = gridDim.x >> 3;
  int cnt = gcnt[b]; if (cnt > cap) cnt = cap;
  const uint2* reg = binned + (size_t)b * cap;
  for (int i = vb * blockDim.x + threadIdx.x; i < cnt; i += nvb * blockDim.x) {
    uint2 r = reg[i];
    int p = atomicAdd(&cursor[r.y], 1);
    csr_src[p] = (int)r.x;
  }
}

__global__ void scan1_kernel(const int* __restrict__ deg, int* __restrict__ row_off,
                             int* __restrict__ partials, int N) {
  __shared__ int smem[1024];
  int t = threadIdx.x;
  int idx = blockIdx.x * 1024 + t;
  int v = (idx < N) ? (int)(((u32)deg[idx] + 7u) & ~7u) : 0;  // padded
  smem[t] = v;
  __syncthreads();
  for (int off = 1; off < 1024; off <<= 1) {
    int u = (t >= off) ? smem[t - off] : 0;
    __syncthreads();
    smem[t] += u;
    __syncthreads();
  }
  if (idx < N) row_off[idx + 1] = smem[t];
  if (t == 1023) partials[blockIdx.x] = smem[t];
}

__global__ void scan2_kernel(int* __restrict__ partials, int P) {
  __shared__ int smem[1024];
  int t = threadIdx.x;
  int v = (t < P) ? partials[t] : 0;
  smem[t] = v;
  __syncthreads();
  for (int off = 1; off < 1024; off <<= 1) {
    int u = (t >= off) ? smem[t - off] : 0;
    __syncthreads();
    smem[t] += u;
    __syncthreads();
  }
  if (t < P) partials[t] = smem[t];
}

__global__ void scan3_kernel(int* __restrict__ row_off, const int* __restrict__ partials,
                             int* __restrict__ cursor, int N) {
  int b = blockIdx.x;
  int idx = b * 1024 + threadIdx.x;
  if (idx < N) {
    int v = row_off[idx + 1] + ((b > 0) ? partials[b - 1] : 0);
    row_off[idx + 1] = v;
    if (idx + 1 < N) cursor[idx + 1] = v;
  }
  if (idx == 0) { row_off[0] = 0; cursor[0] = 0; }
}

__global__ void padC_kernel(const int* __restrict__ row_off, const int* __restrict__ cursor,
                            int* __restrict__ csr_src, int N, int dummy) {
  int i = blockIdx.x * blockDim.x + threadIdx.x;
  if (i >= N) return;
  int e = row_off[i + 1];
  for (int p = cursor[i]; p < e; ++p) csr_src[p] = dummy;
}

// ------------------------------------------------ fused gather_k + proj_{k+1}
// Round-5 proven body (direct per-lane loads; h-loads depend only on csr load)
// + bijective XCD tile swizzle (CSR is dst-binned per XCD -> csr/row_off/a_dst
// reads and hout writes become XCD-L2-local).
__global__ void __launch_bounds__(256) fusedFG_kernel(
    const u16* __restrict__ hin, const float* __restrict__ asi,
    const float* __restrict__ adi, u16* __restrict__ hout,
    float* __restrict__ aso, float* __restrict__ ado,
    const int* __restrict__ row_off, const int* __restrict__ csr_src,
    const float* __restrict__ pf, const u16* __restrict__ wfrag, int N) {
  __shared__ u16 xs[16][72];        // staged tile, row-padded for LDS banks
  __shared__ float sred[2][16][4];  // a partials [sel][row][wave]

  int tid = threadIdx.x;
  int lane = tid & 63;
  int w = tid >> 6;            // wave 0..3 = feature block (proj) / node quad (gather)
  int quad = lane >> 4, m = lane & 15;
  int grp = lane >> 4;         // gather: dst sub-group 0..3
  int eg = (lane >> 3) & 1;    // gather: edge parity
  int fg = lane & 7;           // gather: feature octet
  int tile = xcd_swz((int)blockIdx.x, (int)gridDim.x);
  int row_in = w * 4 + grp;
  int i = tile * 16 + row_in;
  bool valid = i < N;

  short8 bf0 = *(const short8*)(wfrag + (2 * w + 0) * 512 + lane * 8);
  short8 bf1 = *(const short8*)(wfrag + (2 * w + 1) * 512 + lane * 8);
  float asw = pf[4096 + 16 * w + m];
  float adw = pf[4160 + 16 * w + m];

  int beg = 0, end = 0;
  float advv = 0.f;
  if (valid) { beg = row_off[i]; end = row_off[i + 1]; advv = adi[i]; }

  f32x2 acc0 = {0.f, 0.f}, acc1 = {0.f, 0.f}, acc2 = {0.f, 0.f}, acc3 = {0.f, 0.f};
  float den = 0.f;
  for (int b0 = beg; b0 < end; b0 += 8) {
    int eA = b0 + eg;
    int sA = csr_src[eA];
    int sB = csr_src[eA + 2];
    int sC = csr_src[eA + 4];
    int sD = csr_src[eA + 6];
    float aA = asi[sA];
    float aB = asi[sB];
    float aC = asi[sC];
    float aD = asi[sD];
    uint4 hA = ((const uint4*)(hin + (size_t)sA * 64))[fg];
    uint4 hB = ((const uint4*)(hin + (size_t)sB * 64))[fg];
    uint4 hC = ((const uint4*)(hin + (size_t)sC * 64))[fg];
    uint4 hD = ((const uint4*)(hin + (size_t)sD * 64))[fg];

    float tA = aA + advv; tA = (tA > 0.f) ? tA : LRELU_SLOPE * tA;
    float tB = aB + advv; tB = (tB > 0.f) ? tB : LRELU_SLOPE * tB;
    float tC = aC + advv; tC = (tC > 0.f) ? tC : LRELU_SLOPE * tC;
    float tD = aD + advv; tD = (tD > 0.f) ? tD : LRELU_SLOPE * tD;
    float wA = __expf(fminf(tA, 60.f));  // dummy slots: exp(-2e29) == 0 exactly
    float wB = __expf(fminf(tB, 60.f));
    float wC = __expf(fminf(tC, 60.f));
    float wD = __expf(fminf(tD, 60.f));
    den += (wA + wB) + (wC + wD);
    f32x2 wA2 = {wA, wA}, wB2 = {wB, wB}, wC2 = {wC, wC}, wD2 = {wD, wD};
    acc0 += wA2 * up2(hA.x); acc0 += wB2 * up2(hB.x);
    acc0 += wC2 * up2(hC.x); acc0 += wD2 * up2(hD.x);
    acc1 += wA2 * up2(hA.y); acc1 += wB2 * up2(hB.y);
    acc1 += wC2 * up2(hC.y); acc1 += wD2 * up2(hD.y);
    acc2 += wA2 * up2(hA.z); acc2 += wB2 * up2(hB.z);
    acc2 += wC2 * up2(hC.z); acc2 += wD2 * up2(hD.z);
    acc3 += wA2 * up2(hA.w); acc3 += wB2 * up2(hB.w);
    acc3 += wC2 * up2(hC.w); acc3 += wD2 * up2(hD.w);
  }
  den += __shfl_xor(den, 8, 64);
#pragma unroll
  for (int c = 0; c < 2; ++c) {
    acc0[c] += __shfl_xor(acc0[c], 8, 64);
    acc1[c] += __shfl_xor(acc1[c], 8, 64);
    acc2[c] += __shfl_xor(acc2[c], 8, 64);
    acc3[c] += __shfl_xor(acc3[c], 8, 64);
  }
  float inv = (den > 0.f) ? 1.f / den : 0.f;
  float oa[8] = {acc0[0], acc0[1], acc1[0], acc1[1],
                 acc2[0], acc2[1], acc3[0], acc3[1]};

  // stage biased bf16 row into LDS for the fused proj
  if (!eg) {
    u32 o[4];
    if (valid) {
#pragma unroll
      for (int j = 0; j < 4; ++j) {
        float v0 = oa[2 * j]     * inv + pf[4224 + 8 * fg + 2 * j];
        float v1 = oa[2 * j + 1] * inv + pf[4224 + 8 * fg + 2 * j + 1];
        o[j] = (u32)f2bf(v0) | ((u32)f2bf(v1) << 16);
      }
    } else {
      o[0] = o[1] = o[2] = o[3] = 0u;
    }
    *(uint4*)&xs[row_in][fg * 8] = make_uint4(o[0], o[1], o[2], o[3]);
  }
  __syncthreads();

  // proj: wave w computes feature block w for all 16 rows
  short8 a0 = *(const short8*)&xs[m][8 * quad];
  short8 a1 = *(const short8*)&xs[m][32 + 8 * quad];
  f32x4 z = {0.f, 0.f, 0.f, 0.f};
  z = __builtin_amdgcn_mfma_f32_16x16x32_bf16(a0, bf0, z, 0, 0, 0);
  z = __builtin_amdgcn_mfma_f32_16x16x32_bf16(a1, bf1, z, 0, 0, 0);
#pragma unroll
  for (int r = 0; r < 4; ++r) {
    int row = tile * 16 + 4 * quad + r;
    if (row < N) hout[(size_t)row * 64 + 16 * w + m] = f2bf(z[r]);
    float s1 = z[r] * asw, s2 = z[r] * adw;
#pragma unroll
    for (int msk = 1; msk <= 8; msk <<= 1) {
      s1 += __shfl_xor(s1, msk, 64);
      s2 += __shfl_xor(s2, msk, 64);
    }
    if (m == 0) { sred[0][4 * quad + r][w] = s1; sred[1][4 * quad + r][w] = s2; }
  }
  __syncthreads();
  if (tid < 32) {
    int row = tid & 15, sel = tid >> 4;
    float v = sred[sel][row][0] + sred[sel][row][1] + sred[sel][row][2] + sred[sel][row][3];
    int gr = tile * 16 + row;
    if (gr < N) (sel ? ado : aso)[gr] = v;
  }
}

// ------------------------------------------------ final gather -> d_out
// Round-5 proven body + XCD tile swizzle.
__global__ void __launch_bounds__(256) gatherL_kernel(
    const u16* __restrict__ h, const float* __restrict__ a_src,
    const float* __restrict__ a_dst, const int* __restrict__ row_off,
    const int* __restrict__ csr_src, const float* __restrict__ pf,
    void* __restrict__ dout, int N, const int* __restrict__ mode) {
  int lane = threadIdx.x & 63;
  int grp = lane >> 4;
  int eg  = (lane >> 3) & 1;
  int fg  = lane & 7;
  int w   = threadIdx.x >> 6;
  int tile = xcd_swz((int)blockIdx.x, (int)gridDim.x);
  int i = tile * 16 + w * 4 + grp;
  bool valid = i < N;

  int beg = 0, end = 0;
  float adv = 0.f;
  if (valid) {
    beg = row_off[i];
    end = row_off[i + 1];
    adv = a_dst[i];
  }

  f32x2 acc0 = {0.f, 0.f}, acc1 = {0.f, 0.f}, acc2 = {0.f, 0.f}, acc3 = {0.f, 0.f};
  float den = 0.f;

  for (int b0 = beg; b0 < end; b0 += 8) {
    int eA = b0 + eg;
    int sA = csr_src[eA];
    int sB = csr_src[eA + 2];
    int sC = csr_src[eA + 4];
    int sD = csr_src[eA + 6];
    float aA = a_src[sA];
    float aB = a_src[sB];
    float aC = a_src[sC];
    float aD = a_src[sD];
    uint4 hA = ((const uint4*)(h + (size_t)sA * 64))[fg];
    uint4 hB = ((const uint4*)(h + (size_t)sB * 64))[fg];
    uint4 hC = ((const uint4*)(h + (size_t)sC * 64))[fg];
    uint4 hD = ((const uint4*)(h + (size_t)sD * 64))[fg];

    float tA = aA + adv; tA = (tA > 0.f) ? tA : LRELU_SLOPE * tA;
    float tB = aB + adv; tB = (tB > 0.f) ? tB : LRELU_SLOPE * tB;
    float tC = aC + adv; tC = (tC > 0.f) ? tC : LRELU_SLOPE * tC;
    float tD = aD + adv; tD = (tD > 0.f) ? tD : LRELU_SLOPE * tD;
    float wA = __expf(fminf(tA, 60.f));
    float wB = __expf(fminf(tB, 60.f));
    float wC = __expf(fminf(tC, 60.f));
    float wD = __expf(fminf(tD, 60.f));
    den += (wA + wB) + (wC + wD);
    f32x2 wA2 = {wA, wA}, wB2 = {wB, wB}, wC2 = {wC, wC}, wD2 = {wD, wD};
    acc0 += wA2 * up2(hA.x); acc0 += wB2 * up2(hB.x);
    acc0 += wC2 * up2(hC.x); acc0 += wD2 * up2(hD.x);
    acc1 += wA2 * up2(hA.y); acc1 += wB2 * up2(hB.y);
    acc1 += wC2 * up2(hC.y); acc1 += wD2 * up2(hD.y);
    acc2 += wA2 * up2(hA.z); acc2 += wB2 * up2(hB.z);
    acc2 += wC2 * up2(hC.z); acc2 += wD2 * up2(hD.z);
    acc3 += wA2 * up2(hA.w); acc3 += wB2 * up2(hB.w);
    acc3 += wC2 * up2(hC.w); acc3 += wD2 * up2(hD.w);
  }

  den += __shfl_xor(den, 8, 64);
#pragma unroll
  for (int c = 0; c < 2; ++c) {
    acc0[c] += __shfl_xor(acc0[c], 8, 64);
    acc1[c] += __shfl_xor(acc1[c], 8, 64);
    acc2[c] += __shfl_xor(acc2[c], 8, 64);
    acc3[c] += __shfl_xor(acc3[c], 8, 64);
  }
  float inv = (den > 0.f) ? 1.f / den : 0.f;

  if (!valid || eg) return;

  float oa[8] = {acc0[0], acc0[1], acc1[0], acc1[1], acc2[0], acc2[1], acc3[0], acc3[1]};
  if (*mode) {
    u32 o[4];
#pragma unroll
    for (int j = 0; j < 4; ++j) {
      float f0 = oa[2 * j]     * inv + pf[4224 + 8 * fg + 2 * j];
      float f1 = oa[2 * j + 1] * inv + pf[4224 + 8 * fg + 2 * j + 1];
      o[j] = (u32)f2bf(f0) | ((u32)f2bf(f1) << 16);
    }
    *(uint4*)((u16*)dout + (size_t)i * 64 + fg * 8) = make_uint4(o[0], o[1], o[2], o[3]);
  } else {
    float o[8];
#pragma unroll
    for (int j = 0; j < 8; ++j)
      o[j] = oa[j] * inv + pf[4224 + 8 * fg + j];
    float* dp = (float*)dout + (size_t)i * 64 + fg * 8;
    *(float4*)(dp)     = make_float4(o[0], o[1], o[2], o[3]);
    *(float4*)(dp + 4) = make_float4(o[4], o[5], o[6], o[7]);
  }
}

// ------------------------------------------------ launcher
extern "C" void kernel_launch(void* const* d_in, const int* in_sizes, int n_in,
                              void* d_out, int out_size, void* d_ws, size_t ws_size,
                              hipStream_t stream) {
  const void* g     = d_in[0];
  const int*  edge  = (const int*)d_in[1];
  const void* Wp    = d_in[2];
  const void* attsp = d_in[3];
  const void* attdp = d_in[4];
  const void* biasp = d_in[5];

  const int D = 64;
  const int N = in_sizes[0] / D;
  const int E = in_sizes[1] / 2;
  const int* src = edge;
  const int* dst = edge + E;

  int nper = (N + 7) / 8;  // dst ids per XCD bucket
  bool fast_csr = (nper <= MAXPER);

  char* ws = (char*)d_ws;
  size_t off = 0;
  auto alloc = [&](size_t bytes) -> char* {
    char* p = ws + off;
    off += (bytes + 255) & ~size_t(255);
    return p;
  };
  size_t h_bytes = (size_t)(N + 1) * D * sizeof(u16);    // +1 dummy row
  u16*   h0       = (u16*)alloc(h_bytes);
  u16*   h1       = (u16*)alloc(h_bytes);
  u32*   slices   = (u32*)alloc((size_t)8 * BPB * nper * sizeof(u32)); // un-aliased
  float* pf       = (float*)alloc(4288 * sizeof(float));
  u16*   wfrag    = (u16*)alloc(4096 * sizeof(u16));
  float* as0      = (float*)alloc((size_t)(N + 1) * sizeof(float));
  float* as1      = (float*)alloc((size_t)(N + 1) * sizeof(float));
  float* ad0      = (float*)alloc((size_t)N * sizeof(float));
  float* ad1      = (float*)alloc((size_t)N * sizeof(float));
  int*   deg      = (int*)alloc((size_t)N * sizeof(int));
  int*   row_off  = (int*)alloc((size_t)(N + 1) * sizeof(int));
  int*   cursor   = (int*)alloc((size_t)N * sizeof(int));
  int*   csr_src  = (int*)alloc(((size_t)E + 8 * (size_t)N) * sizeof(int)); // padded CSR
  int*   partials = (int*)alloc(1024 * sizeof(int));
  int*   mode     = (int*)alloc(256);
  int*   gcnt     = (int*)alloc(256);
  int    cap      = E / 8 + 16384;                               // per-XCD region capacity
  uint2* binned   = (uint2*)alloc((size_t)8 * cap * sizeof(uint2)); // ~9 MB

  dp_kernel<<<1, 256, 0, stream>>>((const u32*)g, 4096, mode, Wp, attsp, attdp, biasp,
                                   pf, wfrag, gcnt);

  if (!fast_csr) hipMemsetAsync(deg, 0, (size_t)N * sizeof(int), stream);
  int abl = (E + 2047) / 2048;  // 8 edges/thread, 256 threads
  int ntiles = (N + 15) / 16;
  int tblocks = (ntiles + 3) / 4;  // 1 tile/wave for proj0

  int nblk = (N + 1023) / 1024;
  if (fast_csr) {
    // binA || proj0 in one fat kernel (both depend only on dp; h0 un-aliased)
    fatBP_kernel<<<abl + tblocks, 256, 0, stream>>>(
        src, dst, gcnt, binned, E, nper, cap, abl,
        g, mode, wfrag, pf, h0, h1, as0, as1, ad0, N);
    histA_kernel<<<8 * BPB, 256, 0, stream>>>(binned, gcnt, slices, nper, cap);
    scan1f_kernel<<<nblk, 1024, 0, stream>>>(slices, row_off, partials, nper, N);
    scan3c_kernel<<<nblk, 1024, 0, stream>>>(row_off, partials, nblk, slices, csr_src,
                                             nper, N, N);
    scatterB_kernel<<<8 * BPB, 256, 0, stream>>>(binned, gcnt, slices, csr_src, nper, cap);
  } else {
    binA_kernel<<<abl, 256, 0, stream>>>(src, dst, gcnt, binned, E, nper, cap);
    hist_local_kernel<<<1024, 256, 0, stream>>>(binned, gcnt, deg, cap);
    scan1_kernel<<<nblk, 1024, 0, stream>>>(deg, row_off, partials, N);
    scan2_kernel<<<1, 1024, 0, stream>>>(partials, nblk);
    scan3_kernel<<<nblk, 1024, 0, stream>>>(row_off, partials, cursor, N);
    scatter_local_kernel<<<1024, 256, 0, stream>>>(binned, gcnt, cursor, csr_src, cap);
    padC_kernel<<<(N + 255) / 256, 256, 0, stream>>>(row_off, cursor, csr_src, N, N);
    proj0_kernel<<<tblocks, 256, 0, stream>>>(g, mode, wfrag, pf, h0, h1, as0, as1, ad0, N);
  }

  // layers 1..3: fused gather_k + proj_{k+1}, one 16-node tile per block
  fusedFG_kernel<<<ntiles, 256, 0, stream>>>(h0, as0, ad0, h1, as1, ad1,
                                             row_off, csr_src, pf, wfrag, N);
  fusedFG_kernel<<<ntiles, 256, 0, stream>>>(h1, as1, ad1, h0, as0, ad0,
                                             row_off, csr_src, pf, wfrag, N);
  fusedFG_kernel<<<ntiles, 256, 0, stream>>>(h0, as0, ad0, h1, as1, ad1,
                                             row_off, csr_src, pf, wfrag, N);

  // layer 4: final gather -> d_out
  gatherL_kernel<<<ntiles, 256, 0, stream>>>(h1, as1, ad1, row_off, csr_src, pf,
                                             d_out, N, mode);
}